// Round 2
// baseline (163.646 us; speedup 1.0000x reference)
//
#include <hip/hip_runtime.h>

#define EPS 1e-7f
#define BLOCK 256
#define GRID 1024
#define ITERS 4
#define TCOL_MASK 16383LL   // T-1, T = 16384

__global__ __launch_bounds__(BLOCK) void reinforce_fused(
    const float* __restrict__ log_probs,
    const float* __restrict__ logits,
    const float* __restrict__ weight,
    float* __restrict__ out,
    unsigned long long* __restrict__ slots,  // 2*GRID slots, published via atomicExch
    unsigned int* __restrict__ count,        // zeroed by memsetAsync
    long long n4)
{
    const float4* __restrict__ lpv = (const float4*)log_probs;
    const float4* __restrict__ zv  = (const float4*)logits;
    const float4* __restrict__ wv  = (const float4*)weight;

    double num = 0.0, den = 0.0;
    const long long stride = (long long)GRID * BLOCK;
    long long i = (long long)blockIdx.x * BLOCK + threadIdx.x;

    // main loop: batch ITERS iterations — all 3*ITERS loads issued up front
    for (; i + (ITERS - 1) * stride < n4; i += ITERS * stride) {
        float4 lp[ITERS], z[ITERS], w[ITERS];
        int s[ITERS];
#pragma unroll
        for (int k = 0; k < ITERS; ++k) {
            const long long idx = i + (long long)k * stride;
            lp[k] = lpv[idx];
            z[k]  = zv[idx];
            w[k]  = wv[idx];
            s[k]  = (int)((idx << 2) & TCOL_MASK);
        }
        float fn = 0.f, fd = 0.f;
#pragma unroll
        for (int k = 0; k < ITERS; ++k) {
            const float r0 = __logf(1.f / (1.f + __expf(-z[k].x)) + EPS);
            const float r1 = __logf(1.f / (1.f + __expf(-z[k].y)) + EPS);
            const float r2 = __logf(1.f / (1.f + __expf(-z[k].z)) + EPS);
            const float r3 = __logf(1.f / (1.f + __expf(-z[k].w)) + EPS);
            const float t0 = w[k].x * w[k].x * r0 * lp[k].x;
            const float t1 = w[k].y * w[k].y * r1 * lp[k].y;
            const float t2 = w[k].z * w[k].z * r2 * lp[k].z;
            const float t3 = w[k].w * w[k].w * r3 * lp[k].w;
            fn += t0 * (float)(s[k] + 1) + t1 * (float)(s[k] + 2)
                + t2 * (float)(s[k] + 3) + t3 * (float)(s[k] + 4);
            fd += (w[k].x + w[k].y) + (w[k].z + w[k].w);
        }
        num += (double)fn;
        den += (double)fd;
    }
    // tail (empty for the benchmark shape; kept for generality)
    for (; i < n4; i += stride) {
        const float4 lp = lpv[i];
        const float4 z  = zv[i];
        const float4 w  = wv[i];
        const int s = (int)((i << 2) & TCOL_MASK);
        const float r0 = __logf(1.f / (1.f + __expf(-z.x)) + EPS);
        const float r1 = __logf(1.f / (1.f + __expf(-z.y)) + EPS);
        const float r2 = __logf(1.f / (1.f + __expf(-z.z)) + EPS);
        const float r3 = __logf(1.f / (1.f + __expf(-z.w)) + EPS);
        num += (double)(w.x * w.x * r0 * lp.x) * (double)(s + 1)
             + (double)(w.y * w.y * r1 * lp.y) * (double)(s + 2)
             + (double)(w.z * w.z * r2 * lp.z) * (double)(s + 3)
             + (double)(w.w * w.w * r3 * lp.w) * (double)(s + 4);
        den += (double)((w.x + w.y) + (w.z + w.w));
    }

    // intra-block reduction: wave butterfly -> LDS -> thread 0
#pragma unroll
    for (int off = 32; off > 0; off >>= 1) {
        num += __shfl_down(num, off, 64);
        den += __shfl_down(den, off, 64);
    }
    __shared__ double s_n[BLOCK / 64], s_d[BLOCK / 64];
    __shared__ int lastFlag;
    const int lane = threadIdx.x & 63;
    const int wid  = threadIdx.x >> 6;
    if (lane == 0) { s_n[wid] = num; s_d[wid] = den; }
    __syncthreads();
    if (threadIdx.x == 0) {
        const double n = (s_n[0] + s_n[1]) + (s_n[2] + s_n[3]);
        const double d = (s_d[0] + s_d[1]) + (s_d[2] + s_d[3]);
        // publish with device-scope atomics (no init needed; safe across XCD L2s)
        atomicExch(&slots[2 * blockIdx.x],     (unsigned long long)__double_as_longlong(n));
        atomicExch(&slots[2 * blockIdx.x + 1], (unsigned long long)__double_as_longlong(d));
        __threadfence();
        const unsigned int old = atomicAdd(count, 1u);
        lastFlag = (old == (unsigned int)(gridDim.x - 1)) ? 1 : 0;
    }
    __syncthreads();

    // last block to finish folds the per-block partials and writes the result
    if (lastFlag) {
        __threadfence();
        double n = 0.0, d = 0.0;
        for (int j = threadIdx.x; j < GRID; j += BLOCK) {
            n += __longlong_as_double((long long)atomicAdd(&slots[2 * j],     0ULL));
            d += __longlong_as_double((long long)atomicAdd(&slots[2 * j + 1], 0ULL));
        }
#pragma unroll
        for (int off = 32; off > 0; off >>= 1) {
            n += __shfl_down(n, off, 64);
            d += __shfl_down(d, off, 64);
        }
        if (lane == 0) { s_n[wid] = n; s_d[wid] = d; }
        __syncthreads();
        if (threadIdx.x == 0) {
            const double nn = (s_n[0] + s_n[1]) + (s_n[2] + s_n[3]);
            const double dd = (s_d[0] + s_d[1]) + (s_d[2] + s_d[3]);
            out[0] = (float)(nn / dd);
        }
    }
}

extern "C" void kernel_launch(void* const* d_in, const int* in_sizes, int n_in,
                              void* d_out, int out_size, void* d_ws, size_t ws_size,
                              hipStream_t stream) {
    const float* log_probs = (const float*)d_in[0];
    const float* logits    = (const float*)d_in[1];
    const float* weight    = (const float*)d_in[2];
    float* out = (float*)d_out;

    unsigned long long* slots = (unsigned long long*)d_ws;        // 2*GRID * 8 bytes
    unsigned int* count = (unsigned int*)((char*)d_ws + 2 * GRID * sizeof(unsigned long long));

    const long long N  = (long long)in_sizes[0];  // B*T
    const long long n4 = N >> 2;

    // only the counter needs zeroing; slots are overwritten via atomicExch
    hipMemsetAsync(count, 0, sizeof(unsigned int), stream);

    reinforce_fused<<<GRID, BLOCK, 0, stream>>>(log_probs, logits, weight,
                                                out, slots, count, n4);
}

// Round 3
// 117.233 us; speedup vs baseline: 1.3959x; 1.3959x over previous
//
#include <hip/hip_runtime.h>

#define EPS 1e-7f
#define BLOCK 256
#define ITERS 4
#define TCOL_MASK 16383LL   // T-1, T = 16384 (bench shape)

// Per-block partials: ws[2*b] = num, ws[2*b+1] = den (plain stores, no atomics).

__global__ __launch_bounds__(BLOCK, 8) void reinforce_partial(
    const float* __restrict__ log_probs,
    const float* __restrict__ logits,
    const float* __restrict__ weight,
    double* __restrict__ parts,
    long long n4)
{
    const float4* __restrict__ lpv = (const float4*)log_probs;
    const float4* __restrict__ zv  = (const float4*)logits;
    const float4* __restrict__ wv  = (const float4*)weight;

    // block-contiguous: block b owns float4 indices [b*1024, b*1024+1023]
    const long long base = (long long)blockIdx.x * (BLOCK * ITERS) + threadIdx.x;

    double num = 0.0, den = 0.0;

    // software pipeline: prefetch iter 0, then load j+1 before computing j
    float4 lp, zz, ww;
    bool v0 = base < n4;
    if (v0) { lp = lpv[base]; zz = zv[base]; ww = wv[base]; }

#pragma unroll
    for (int j = 0; j < ITERS; ++j) {
        const long long cur = base + (long long)j * BLOCK;
        const bool valid = cur < n4;

        float4 nlp, nz, nw;
        if (j + 1 < ITERS) {
            const long long nx = cur + BLOCK;
            if (nx < n4) { nlp = lpv[nx]; nz = zv[nx]; nw = wv[nx]; }
        }

        if (valid) {
            const int s = (int)((cur << 2) & TCOL_MASK);
            const float r0 = __logf(1.f / (1.f + __expf(-zz.x)) + EPS);
            const float r1 = __logf(1.f / (1.f + __expf(-zz.y)) + EPS);
            const float r2 = __logf(1.f / (1.f + __expf(-zz.z)) + EPS);
            const float r3 = __logf(1.f / (1.f + __expf(-zz.w)) + EPS);
            const float t0 = ww.x * ww.x * r0 * lp.x;
            const float t1 = ww.y * ww.y * r1 * lp.y;
            const float t2 = ww.z * ww.z * r2 * lp.z;
            const float t3 = ww.w * ww.w * r3 * lp.w;
            const float fn = t0 * (float)(s + 1) + t1 * (float)(s + 2)
                           + t2 * (float)(s + 3) + t3 * (float)(s + 4);
            const float fd = (ww.x + ww.y) + (ww.z + ww.w);
            num += (double)fn;
            den += (double)fd;
        }
        lp = nlp; zz = nz; ww = nw;
    }

    // intra-block reduction: wave butterfly -> LDS -> thread 0 plain store
#pragma unroll
    for (int off = 32; off > 0; off >>= 1) {
        num += __shfl_down(num, off, 64);
        den += __shfl_down(den, off, 64);
    }
    __shared__ double s_n[BLOCK / 64], s_d[BLOCK / 64];
    const int lane = threadIdx.x & 63;
    const int wid  = threadIdx.x >> 6;
    if (lane == 0) { s_n[wid] = num; s_d[wid] = den; }
    __syncthreads();
    if (threadIdx.x == 0) {
        const double n = (s_n[0] + s_n[1]) + (s_n[2] + s_n[3]);
        const double d = (s_d[0] + s_d[1]) + (s_d[2] + s_d[3]);
        parts[2 * blockIdx.x]     = n;
        parts[2 * blockIdx.x + 1] = d;
    }
}

__global__ __launch_bounds__(BLOCK) void reinforce_finalize(
    const double* __restrict__ parts, float* __restrict__ out, int nblocks)
{
    double n = 0.0, d = 0.0;
    for (int j = threadIdx.x; j < nblocks; j += BLOCK) {
        n += parts[2 * j];
        d += parts[2 * j + 1];
    }
#pragma unroll
    for (int off = 32; off > 0; off >>= 1) {
        n += __shfl_down(n, off, 64);
        d += __shfl_down(d, off, 64);
    }
    __shared__ double s_n[BLOCK / 64], s_d[BLOCK / 64];
    const int lane = threadIdx.x & 63;
    const int wid  = threadIdx.x >> 6;
    if (lane == 0) { s_n[wid] = n; s_d[wid] = d; }
    __syncthreads();
    if (threadIdx.x == 0) {
        const double nn = (s_n[0] + s_n[1]) + (s_n[2] + s_n[3]);
        const double dd = (s_d[0] + s_d[1]) + (s_d[2] + s_d[3]);
        out[0] = (float)(nn / dd);
    }
}

extern "C" void kernel_launch(void* const* d_in, const int* in_sizes, int n_in,
                              void* d_out, int out_size, void* d_ws, size_t ws_size,
                              hipStream_t stream) {
    const float* log_probs = (const float*)d_in[0];
    const float* logits    = (const float*)d_in[1];
    const float* weight    = (const float*)d_in[2];
    float* out = (float*)d_out;
    double* parts = (double*)d_ws;

    const long long N  = (long long)in_sizes[0];  // B*T = 8,388,608
    const long long n4 = N >> 2;                  // 2,097,152 float4s

    // exact fit for bench shape: 2,097,152 / (256*4) = 2048 blocks (8/CU)
    const int grid = (int)((n4 + (long long)(BLOCK * ITERS) - 1) / (BLOCK * ITERS));

    reinforce_partial<<<grid, BLOCK, 0, stream>>>(log_probs, logits, weight, parts, n4);
    reinforce_finalize<<<1, BLOCK, 0, stream>>>(parts, out, grid);
}